// Round 8
// baseline (2033.712 us; speedup 1.0000x reference)
//
#include <hip/hip_runtime.h>
#include <hip/hip_bf16.h>
#include <math.h>

#define B_ 4
#define N_ 2048
#define D_ 1024
#define WIN_ 4
#define KTOP 8
#define ALPHA_ 0.3f
#define SCALE_ (1.0f/32.0f)
#define NCH 16          // N_/128 col chunks
#define TROW 36         // ushorts per LDS tile row (72B stride)

typedef unsigned short ushortT;
typedef __attribute__((ext_vector_type(8))) short short8v;   // 8 bf16 (4 VGPR)
typedef __attribute__((ext_vector_type(4))) float f32x4;

__device__ inline ushortT f2b(float f) {     // f32 -> bf16 RNE
    unsigned int u = __float_as_uint(f);
    unsigned int r = (u + 0x7fffu + ((u >> 16) & 1u)) >> 16;
    return (ushortT)r;
}
__device__ inline float b2f(ushortT u) {
    return __uint_as_float(((unsigned int)u) << 16);
}

// ---------------------------------------------------------------------------
// mu f32 -> 3 bf16 planes: a contiguous, b contiguous, c STRIDED into CCb's
// right half (row*2048 + 1024 + col).
// ---------------------------------------------------------------------------
__global__ __launch_bounds__(256)
void split3_mu(const float* __restrict__ src, ushortT* __restrict__ Pa,
               ushortT* __restrict__ Pb, ushortT* __restrict__ CCbase)
{
    size_t base = ((size_t)blockIdx.x * 256 + threadIdx.x) * 4;
    int row = (int)(base >> 10);
    int col = (int)(base & 1023);
    float4 v = *reinterpret_cast<const float4*>(&src[base]);
    ushort4 pa, pb, pc;
    float vv[4] = {v.x, v.y, v.z, v.w};
#pragma unroll
    for (int j = 0; j < 4; ++j) {
        float f = vv[j];
        ushortT a = f2b(f);  float r1 = f - b2f(a);
        ushortT b = f2b(r1); float r2 = r1 - b2f(b);
        ushortT c = f2b(r2);
        ((ushortT*)&pa)[j] = a; ((ushortT*)&pb)[j] = b; ((ushortT*)&pc)[j] = c;
    }
    *reinterpret_cast<ushort4*>(&Pa[base]) = pa;
    *reinterpret_cast<ushort4*>(&Pb[base]) = pb;
    *reinterpret_cast<ushort4*>(&CCbase[(size_t)row * 2048 + 1024 + col]) = pc;
}

// ---------------------------------------------------------------------------
// W [K][Nn] f32 -> Wt [Nn][K] bf16 (single plane)
// ---------------------------------------------------------------------------
__global__ __launch_bounds__(256)
void transpose_f2b(const float* __restrict__ W, ushortT* __restrict__ Wt,
                   int K, int Nn)
{
    __shared__ float t[32][33];
    const int k0 = blockIdx.x * 32, n0 = blockIdx.y * 32;
    const int tx = threadIdx.x & 31, ty8 = threadIdx.x >> 5;
#pragma unroll
    for (int p = 0; p < 4; ++p) {
        int kk = p * 8 + ty8;
        t[kk][tx] = W[(size_t)(k0 + kk) * Nn + n0 + tx];
    }
    __syncthreads();
#pragma unroll
    for (int p = 0; p < 4; ++p) {
        int nn = p * 8 + ty8;
        Wt[(size_t)(n0 + nn) * K + k0 + tx] = f2b(t[tx][nn]);
    }
}

// ---------------------------------------------------------------------------
// W [K][Nn] f32 -> 3 transposed bf16 planes [Nn][K]
// ---------------------------------------------------------------------------
__global__ __launch_bounds__(256)
void transpose_split3(const float* __restrict__ W, ushortT* __restrict__ Pa,
                      ushortT* __restrict__ Pb, ushortT* __restrict__ Pc,
                      int K, int Nn)
{
    __shared__ float t[32][33];
    const int k0 = blockIdx.x * 32, n0 = blockIdx.y * 32;
    const int tx = threadIdx.x & 31, ty8 = threadIdx.x >> 5;
#pragma unroll
    for (int p = 0; p < 4; ++p) {
        int kk = p * 8 + ty8;
        t[kk][tx] = W[(size_t)(k0 + kk) * Nn + n0 + tx];
    }
    __syncthreads();
#pragma unroll
    for (int p = 0; p < 4; ++p) {
        int nn = p * 8 + ty8;
        float f = t[tx][nn];
        ushortT a = f2b(f);  float r1 = f - b2f(a);
        ushortT b = f2b(r1); float r2 = r1 - b2f(b);
        ushortT c = f2b(r2);
        size_t o = (size_t)(n0 + nn) * K + k0 + tx;
        Pa[o] = a; Pb[o] = b; Pc[o] = c;
    }
}

// ---------------------------------------------------------------------------
// bf16 MFMA GEMM (proven): 128x128 tile, BK=64, 4 waves, 64x64/wave.
// ---------------------------------------------------------------------------
template<int BF16OUT>
__global__ __launch_bounds__(256)
void mfma_gemm(const ushortT* __restrict__ A, int lda,
               const ushortT* __restrict__ Bt, int ldb,
               const float* __restrict__ bias,
               void* __restrict__ Cout, int ldc, int K)
{
    __shared__ ushortT AsL[128 * 72];
    __shared__ ushortT BsL[128 * 72];
    const int tid = threadIdx.x;
    const int m0 = blockIdx.y * 128;
    const int n0 = blockIdx.x * 128;
    const int w = tid >> 6, lane = tid & 63;
    const int wr = w >> 1, wc = w & 1;

    f32x4 acc[4][4];
#pragma unroll
    for (int mi = 0; mi < 4; ++mi)
#pragma unroll
        for (int ni = 0; ni < 4; ++ni) acc[mi][ni] = (f32x4){0.f, 0.f, 0.f, 0.f};

    for (int k0 = 0; k0 < K; k0 += 64) {
#pragma unroll
        for (int it = 0; it < 4; ++it) {
            int idx = tid + it * 256;        // 0..1023
            int row = idx >> 3, c = idx & 7;
            int4 va = *reinterpret_cast<const int4*>(&A[(size_t)(m0 + row) * lda + k0 + c * 8]);
            *reinterpret_cast<int4*>(&AsL[row * 72 + c * 8]) = va;
            int4 vb = *reinterpret_cast<const int4*>(&Bt[(size_t)(n0 + row) * ldb + k0 + c * 8]);
            *reinterpret_cast<int4*>(&BsL[row * 72 + c * 8]) = vb;
        }
        __syncthreads();
#pragma unroll
        for (int kh = 0; kh < 2; ++kh) {
            const int ko = kh * 32 + (lane >> 4) * 8;
            const int rr = lane & 15;
            short8v af[4], bf[4];
#pragma unroll
            for (int mi = 0; mi < 4; ++mi)
                af[mi] = *reinterpret_cast<const short8v*>(&AsL[(wr * 64 + mi * 16 + rr) * 72 + ko]);
#pragma unroll
            for (int ni = 0; ni < 4; ++ni)
                bf[ni] = *reinterpret_cast<const short8v*>(&BsL[(wc * 64 + ni * 16 + rr) * 72 + ko]);
#pragma unroll
            for (int mi = 0; mi < 4; ++mi)
#pragma unroll
                for (int ni = 0; ni < 4; ++ni)
                    acc[mi][ni] = __builtin_amdgcn_mfma_f32_16x16x32_bf16(
                        af[mi], bf[ni], acc[mi][ni], 0, 0, 0);
        }
        __syncthreads();
    }

    const int r4 = (lane >> 4) * 4, cl = lane & 15;
#pragma unroll
    for (int mi = 0; mi < 4; ++mi)
#pragma unroll
        for (int ni = 0; ni < 4; ++ni) {
            int row = m0 + wr * 64 + mi * 16 + r4;
            int col = n0 + wc * 64 + ni * 16 + cl;
            float bb = bias ? bias[col] : 0.f;
#pragma unroll
            for (int r = 0; r < 4; ++r) {
                float v = acc[mi][ni][r] + bb;
                if (BF16OUT)
                    ((ushortT*)Cout)[(size_t)(row + r) * ldc + col] = f2b(v);
                else
                    ((float*)Cout)[(size_t)(row + r) * ldc + col] = v;
            }
        }
}

// ---------------------------------------------------------------------------
// S[b,n,:] = mean_w silu(A + Nb shifted), output bf16.
// ---------------------------------------------------------------------------
__global__ __launch_bounds__(256)
void silu_mean(const float* __restrict__ A, const float* __restrict__ Nb,
               ushortT* __restrict__ Sb)
{
    size_t idx4 = (size_t)blockIdx.x * blockDim.x + threadIdx.x;
    size_t base = idx4 << 2;
    int n = (int)((base >> 10) & (N_ - 1));
    float4 a = *reinterpret_cast<const float4*>(&A[base]);
    float sx = 0.f, sy = 0.f, sz = 0.f, sw = 0.f;
#pragma unroll
    for (int w = 1; w <= WIN_; ++w) {
        float xx = a.x, xy = a.y, xz = a.z, xw = a.w;
        if (n >= w) {
            const float4 nb = *reinterpret_cast<const float4*>(&Nb[base - (size_t)w * D_]);
            xx += nb.x; xy += nb.y; xz += nb.z; xw += nb.w;
        }
        sx += xx / (1.f + __expf(-xx));
        sy += xy / (1.f + __expf(-xy));
        sz += xz / (1.f + __expf(-xz));
        sw += xw / (1.f + __expf(-xw));
    }
    ushort4 o = {f2b(sx * 0.25f), f2b(sy * 0.25f), f2b(sz * 0.25f), f2b(sw * 0.25f)};
    *reinterpret_cast<ushort4*>(&Sb[base]) = o;
}

// ---------------------------------------------------------------------------
__device__ inline void topk_insert(float (&tv)[KTOP], int (&ti)[KTOP], float s, int m)
{
    if ((s > tv[KTOP-1]) || (s == tv[KTOP-1] && m < ti[KTOP-1])) {
        float cs = s; int ci = m;
#pragma unroll
        for (int q = 0; q < KTOP; ++q) {
            bool beats = (cs > tv[q]) || (cs == tv[q] && ci < ti[q]);
            if (beats) { float t0 = tv[q]; int t1 = ti[q];
                         tv[q] = cs; ti[q] = ci; cs = t0; ci = t1; }
        }
    }
}

// ---------------------------------------------------------------------------
// 6-product split-MFMA core, 64x64 wave tile (wr, wc in {0,1}), acc[4][4].
// All 12 A-fragments live -> 24 ds_read_b128 feed 96 MFMAs (4 MFMA/read).
// Products kept: p+q<=2 (ah, al, am, bh, bl, ch).
// ---------------------------------------------------------------------------
#define SPLIT6_COMPUTE64(T6, wr, wc, lane, acc)                                 \
    {                                                                           \
        const int rr_ = (lane) & 15, ko_ = ((lane) >> 4) * 8;                   \
        short8v aF_[3][4];                                                      \
        _Pragma("unroll")                                                       \
        for (int p_ = 0; p_ < 3; ++p_) {                                        \
            _Pragma("unroll")                                                   \
            for (int mi_ = 0; mi_ < 4; ++mi_)                                   \
                aF_[p_][mi_] = *reinterpret_cast<const short8v*>(               \
                    &T6[p_ * 4608 + ((wr) * 64 + mi_ * 16 + rr_) * TROW + ko_]);\
        }                                                                       \
        _Pragma("unroll")                                                       \
        for (int q_ = 0; q_ < 3; ++q_) {                                        \
            short8v bF_[4];                                                     \
            _Pragma("unroll")                                                   \
            for (int ni_ = 0; ni_ < 4; ++ni_)                                   \
                bF_[ni_] = *reinterpret_cast<const short8v*>(                   \
                    &T6[(3 + q_) * 4608 + ((wc) * 64 + ni_ * 16 + rr_) * TROW + ko_]); \
            _Pragma("unroll")                                                   \
            for (int p_ = 0; p_ < 3 - q_; ++p_) {                               \
                _Pragma("unroll")                                               \
                for (int mi_ = 0; mi_ < 4; ++mi_)                               \
                    _Pragma("unroll")                                           \
                    for (int ni_ = 0; ni_ < 4; ++ni_)                           \
                        acc[mi_][ni_] = __builtin_amdgcn_mfma_f32_16x16x32_bf16(\
                            aF_[p_][mi_], bF_[ni_], acc[mi_][ni_], 0, 0, 0);    \
            }                                                                   \
        }                                                                       \
    }

// stage helpers: 256 threads, 6 tiles of 128x32 bf16; thread covers one row,
// two adjacent 16B chunks (cL2, cL2+1).
#define SPLIT6_LOAD(sreg, P0, P1, P2, P3, P4, P5, oA, oAc, oB, kk)              \
    {                                                                           \
        sreg[0][0] = *reinterpret_cast<const int4*>(&P0[oA + (kk)]);            \
        sreg[0][1] = *reinterpret_cast<const int4*>(&P0[oA + (kk) + 8]);        \
        sreg[1][0] = *reinterpret_cast<const int4*>(&P1[oA + (kk)]);            \
        sreg[1][1] = *reinterpret_cast<const int4*>(&P1[oA + (kk) + 8]);        \
        sreg[2][0] = *reinterpret_cast<const int4*>(&P2[oAc + (kk)]);           \
        sreg[2][1] = *reinterpret_cast<const int4*>(&P2[oAc + (kk) + 8]);       \
        sreg[3][0] = *reinterpret_cast<const int4*>(&P3[oB + (kk)]);            \
        sreg[3][1] = *reinterpret_cast<const int4*>(&P3[oB + (kk) + 8]);        \
        sreg[4][0] = *reinterpret_cast<const int4*>(&P4[oB + (kk)]);            \
        sreg[4][1] = *reinterpret_cast<const int4*>(&P4[oB + (kk) + 8]);        \
        sreg[5][0] = *reinterpret_cast<const int4*>(&P5[oB + (kk)]);            \
        sreg[5][1] = *reinterpret_cast<const int4*>(&P5[oB + (kk) + 8]);        \
    }

#define SPLIT6_STORE(sreg, ldst)                                                \
    {                                                                           \
        _Pragma("unroll")                                                       \
        for (int t_ = 0; t_ < 6; ++t_) {                                        \
            *reinterpret_cast<int4*>(&T6[t_ * 4608 + (ldst)]) = sreg[t_][0];    \
            *reinterpret_cast<int4*>(&T6[t_ * 4608 + (ldst) + 8]) = sreg[t_][1];\
        }                                                                       \
    }

// ---------------------------------------------------------------------------
// gemm_split6: out = (A0+A1+A2) @ (B0+B1+B2)^T + bias, 6 kept products,
// f32-equivalent. 256 thr, 4 waves 64x64, BK=32, reg-prefetch, XCD swizzle.
// Output split into 3 bf16 planes.
// ---------------------------------------------------------------------------
__global__ __launch_bounds__(256, 2)
void gemm_split6(const ushortT* __restrict__ A0, const ushortT* __restrict__ A1,
                 const ushortT* __restrict__ A2, int lda, int ldac,
                 const ushortT* __restrict__ B0, const ushortT* __restrict__ B1,
                 const ushortT* __restrict__ B2,
                 const float* __restrict__ bias,
                 ushortT* __restrict__ Pa, ushortT* __restrict__ Pb,
                 ushortT* __restrict__ Pc)
{
    __shared__ ushortT T6[6 * 128 * TROW];     // 55296 B

    int lin = blockIdx.y * 8 + blockIdx.x;                // 0..511
    lin = (lin & 7) * 64 + (lin >> 3);                    // XCD-chunked
    const int m0 = (lin >> 3) * 128;
    const int n0 = (lin & 7) * 128;

    const int tid = threadIdx.x;
    const int wid = tid >> 6, lane = tid & 63;
    const int wr = wid >> 1, wc = wid & 1;
    const int rowL = tid >> 1;                 // 0..127
    const int cL2  = (tid & 1) * 16;           // ushort offset of 32B pair

    const size_t offA  = (size_t)(m0 + rowL) * lda + cL2;
    const size_t offAc = (size_t)(m0 + rowL) * ldac + cL2;
    const size_t offB  = (size_t)(n0 + rowL) * D_ + cL2;
    const int ldst = rowL * TROW + cL2;

    f32x4 acc[4][4];
#pragma unroll
    for (int mi = 0; mi < 4; ++mi)
#pragma unroll
        for (int ni = 0; ni < 4; ++ni) acc[mi][ni] = (f32x4){0,0,0,0};

    int4 s[6][2];
    SPLIT6_LOAD(s, A0, A1, A2, B0, B1, B2, offA, offAc, offB, 0)

    for (int ks = 0; ks < 32; ++ks) {
        __syncthreads();
        SPLIT6_STORE(s, ldst)
        __syncthreads();
        if (ks < 31) {
            const int kk = (ks + 1) * 32;
            SPLIT6_LOAD(s, A0, A1, A2, B0, B1, B2, offA, offAc, offB, kk)
        }
        SPLIT6_COMPUTE64(T6, wr, wc, lane, acc)
    }

    const int r4 = (lane >> 4) * 4, cl = lane & 15;
#pragma unroll
    for (int mi = 0; mi < 4; ++mi)
#pragma unroll
        for (int ni = 0; ni < 4; ++ni) {
            int col = n0 + wc * 64 + ni * 16 + cl;
            float bb = bias[col];
#pragma unroll
            for (int r = 0; r < 4; ++r) {
                int row = m0 + wr * 64 + mi * 16 + r4 + r;
                float v = acc[mi][ni][r] + bb;
                ushortT a = f2b(v);  float r1 = v - b2f(a);
                ushortT b = f2b(r1); float r2 = r1 - b2f(b);
                ushortT c = f2b(r2);
                size_t o = (size_t)row * D_ + col;
                Pa[o] = a; Pb[o] = b; Pc[o] = c;
            }
        }
}

// ---------------------------------------------------------------------------
// attn_scores_mfma2: 6-product split scores + mask + pheromone + per-chunk
// top-8. 256 thr, 4 waves 64x64, BK=32, reg-prefetch, XCD swizzle.
// ---------------------------------------------------------------------------
__global__ __launch_bounds__(256, 2)
void attn_scores_mfma2(const ushortT* __restrict__ Qa, const ushortT* __restrict__ Qb2,
                       const ushortT* __restrict__ Qc,
                       const ushortT* __restrict__ Ka, const ushortT* __restrict__ Kb2,
                       const ushortT* __restrict__ Kc,
                       const float* __restrict__ pher,
                       float* __restrict__ WV, int* __restrict__ WI)
{
    __shared__ ushortT T6[6 * 128 * TROW];     // 55296 B
    __shared__ float Ps[128];
    float* MV = reinterpret_cast<float*>(&T6[0]);                    // [32][128]
    int*   MI = reinterpret_cast<int*>((char*)&T6[0] + 16384);       // [32][128]
    float* PV = reinterpret_cast<float*>((char*)&T6[0] + 32768);     // [32][4][8]
    int*   PI = reinterpret_cast<int*>((char*)&T6[0] + 36864);       // [32][4][8]

    int lin = blockIdx.y * 136 + blockIdx.x;              // 0..543
    lin = (lin & 7) * 68 + (lin >> 3);                    // XCD-chunked, 544=8*68
    const int b = lin / 136;
    const int xy = lin - b * 136;
    int g = 0;
    while ((g + 1) * (g + 2) / 2 <= xy) ++g;
    const int ch = xy - g * (g + 1) / 2;
    const int n0 = g * 128;
    const int m0 = ch * 128;
    const size_t bN = (size_t)b * N_;

    const int tid = threadIdx.x;
    const int wid = tid >> 6, lane = tid & 63;
    const int wr = wid >> 1, wc = wid & 1;
    const int rowL = tid >> 1;
    const int cL2  = (tid & 1) * 16;

    if (tid < 128) Ps[tid] = pher[bN + m0 + tid];

    const size_t offQ = (bN + n0 + rowL) * (size_t)D_ + cL2;
    const size_t offK = (bN + m0 + rowL) * (size_t)D_ + cL2;
    const int ldst = rowL * TROW + cL2;

    f32x4 acc[4][4];
#pragma unroll
    for (int mi = 0; mi < 4; ++mi)
#pragma unroll
        for (int ni = 0; ni < 4; ++ni) acc[mi][ni] = (f32x4){0,0,0,0};

    int4 s[6][2];
    SPLIT6_LOAD(s, Qa, Qb2, Qc, Ka, Kb2, Kc, offQ, offQ, offK, 0)

    for (int ks = 0; ks < 32; ++ks) {
        __syncthreads();
        SPLIT6_STORE(s, ldst)
        __syncthreads();
        if (ks < 31) {
            const int kk = (ks + 1) * 32;
            SPLIT6_LOAD(s, Qa, Qb2, Qc, Ka, Kb2, Kc, offQ, offQ, offK, kk)
        }
        SPLIT6_COMPUTE64(T6, wr, wc, lane, acc)
    }

    // ---- fold to per-row top-8: 4 passes of 32 rows ----
    const int r4 = (lane >> 4) * 4, cl = lane & 15;
    for (int p = 0; p < 4; ++p) {
        __syncthreads();                       // T6/MV consumers done
        if (wr == (p >> 1)) {
#pragma unroll
            for (int mi2 = 0; mi2 < 2; ++mi2) {
                const int mi = (p & 1) * 2 + mi2;
#pragma unroll
                for (int ni = 0; ni < 4; ++ni) {
                    int col = wc * 64 + ni * 16 + cl;
                    int m = m0 + col;
#pragma unroll
                    for (int r = 0; r < 4; ++r) {
                        int rloc = mi2 * 16 + r4 + r;
                        int n = n0 + p * 32 + rloc;
                        bool ok = (m <= n);
                        MV[rloc * 128 + col] = ok ? (acc[mi][ni][r] * SCALE_ + ALPHA_ * Ps[col])
                                                  : -INFINITY;
                        MI[rloc * 128 + col] = ok ? m : 0x7fffffff;
                    }
                }
            }
        }
        __syncthreads();
        if (tid < 128) {                       // partial top-8 over a 32-col quarter
            const int row = tid >> 2, q4 = tid & 3;
            float tv[KTOP]; int ti[KTOP];
#pragma unroll
            for (int j = 0; j < KTOP; ++j) { tv[j] = -INFINITY; ti[j] = 0x7fffffff; }
            for (int j = 0; j < 32; ++j) {
                float s2 = MV[row * 128 + q4 * 32 + j];
                if (s2 == -INFINITY) continue;
                topk_insert(tv, ti, s2, MI[row * 128 + q4 * 32 + j]);
            }
#pragma unroll
            for (int j = 0; j < KTOP; ++j) {
                PV[(row * 4 + q4) * 8 + j] = tv[j];
                PI[(row * 4 + q4) * 8 + j] = ti[j];
            }
        }
        __syncthreads();
        if (tid < 32) {                        // merge 4 partials -> chunk top-8
            float tv[KTOP]; int ti[KTOP];
#pragma unroll
            for (int j = 0; j < KTOP; ++j) { tv[j] = -INFINITY; ti[j] = 0x7fffffff; }
            for (int i = 0; i < 32; ++i) {
                float s2 = PV[tid * 32 + i];
                if (s2 == -INFINITY) continue;
                topk_insert(tv, ti, s2, PI[tid * 32 + i]);
            }
            int n = n0 + p * 32 + tid;
            size_t base = ((bN + n) * NCH + ch) * 8;
#pragma unroll
            for (int j = 0; j < KTOP; ++j) { WV[base + j] = tv[j]; WI[base + j] = ti[j]; }
        }
    }
}

// ---------------------------------------------------------------------------
// attn_merge: merge <=16 chunk lists -> top-8 -> softmax -> gather bf16 V ->
// CCb right half. Grid 2048 blocks, 4 rows each.
// ---------------------------------------------------------------------------
__global__ __launch_bounds__(256)
void attn_merge(const float* __restrict__ WV, const int* __restrict__ WI,
                const ushortT* __restrict__ V, ushortT* __restrict__ CCb)
{
    __shared__ float CV[4][128];
    __shared__ int   CI[4][128];
    __shared__ float Pp[4][KTOP];
    __shared__ int   Pi[4][KTOP];

    const int tid  = threadIdx.x;
    const int wv   = tid >> 6;
    const int lane = tid & 63;
    const int rid  = blockIdx.x * 4 + wv;
    const int b    = rid >> 11;
    const int n    = rid & (N_ - 1);
    const int ncand = ((n >> 7) + 1) * 8;
    const size_t cbase = (size_t)rid * (NCH * 8);

#pragma unroll
    for (int t = 0; t < 2; ++t) {
        int i = lane + t * 64;
        if (i < ncand) { CV[wv][i] = WV[cbase + i]; CI[wv][i] = WI[cbase + i]; }
        else           { CV[wv][i] = -INFINITY;     CI[wv][i] = 0x7fffffff;   }
    }
    __syncthreads();

    if (lane == 0) {
        float tv[KTOP]; int ti[KTOP];
#pragma unroll
        for (int j = 0; j < KTOP; ++j) { tv[j] = -INFINITY; ti[j] = 0x7fffffff; }
        for (int i = 0; i < 128; ++i) {
            float s = CV[wv][i];
            if (s == -INFINITY) continue;
            topk_insert(tv, ti, s, CI[wv][i]);
        }
        float mx = tv[0];
        float e[KTOP]; float sum = 0.f;
#pragma unroll
        for (int j = 0; j < KTOP; ++j) {
            e[j] = (tv[j] == -INFINITY) ? 0.f : __expf(tv[j] - mx);
            sum += e[j];
        }
        float inv = 1.f / sum;
#pragma unroll
        for (int j = 0; j < KTOP; ++j) {
            Pp[wv][j] = e[j] * inv;
            Pi[wv][j] = (tv[j] == -INFINITY) ? 0 : ti[j];
        }
    }
    __syncthreads();

    const size_t vbase = (size_t)b * N_ * D_;
#pragma unroll
    for (int it = 0; it < 2; ++it) {
        int c8 = (it * 64 + lane) * 8;
        float o[8];
#pragma unroll
        for (int u = 0; u < 8; ++u) o[u] = 0.f;
#pragma unroll
        for (int j = 0; j < KTOP; ++j) {
            float p = Pp[wv][j];
            ushort4 v0 = *reinterpret_cast<const ushort4*>(
                &V[vbase + (size_t)Pi[wv][j] * D_ + c8]);
            ushort4 v1 = *reinterpret_cast<const ushort4*>(
                &V[vbase + (size_t)Pi[wv][j] * D_ + c8 + 4]);
            o[0] = fmaf(p, b2f(v0.x), o[0]); o[1] = fmaf(p, b2f(v0.y), o[1]);
            o[2] = fmaf(p, b2f(v0.z), o[2]); o[3] = fmaf(p, b2f(v0.w), o[3]);
            o[4] = fmaf(p, b2f(v1.x), o[4]); o[5] = fmaf(p, b2f(v1.y), o[5]);
            o[6] = fmaf(p, b2f(v1.z), o[6]); o[7] = fmaf(p, b2f(v1.w), o[7]);
        }
        ushort4 ob0 = {f2b(o[0]), f2b(o[1]), f2b(o[2]), f2b(o[3])};
        ushort4 ob1 = {f2b(o[4]), f2b(o[5]), f2b(o[6]), f2b(o[7])};
        *reinterpret_cast<ushort4*>(&CCb[(size_t)rid * 2048 + 1024 + c8]) = ob0;
        *reinterpret_cast<ushort4*>(&CCb[(size_t)rid * 2048 + 1024 + c8 + 4]) = ob1;
    }
}

// ---------------------------------------------------------------------------
extern "C" void kernel_launch(void* const* d_in, const int* in_sizes, int n_in,
                              void* d_out, int out_size, void* d_ws, size_t ws_size,
                              hipStream_t stream)
{
    const float* mu   = (const float*)d_in[0];
    const float* pher = (const float*)d_in[1];
    const float* Wq   = (const float*)d_in[2];
    const float* bq   = (const float*)d_in[3];
    const float* Wk   = (const float*)d_in[4];
    const float* bk   = (const float*)d_in[5];
    const float* Wv   = (const float*)d_in[6];
    const float* bv   = (const float*)d_in[7];
    const float* Wm1  = (const float*)d_in[8];
    const float* bm1  = (const float*)d_in[9];
    const float* Wm2  = (const float*)d_in[10];
    const float* bm2  = (const float*)d_in[11];
    const float* Wo   = (const float*)d_in[12];
    const float* bo   = (const float*)d_in[13];
    float* out = (float*)d_out;
    float* ws  = (float*)d_ws;

    const size_t SZ  = (size_t)B_ * N_ * D_;    // 8388608 floats
    const size_t MEG = 1024 * 1024;             // floats
    const int M = B_ * N_;                      // 8192

    // ---- workspace map (float units), total 5.5*SZ + 3*MEG ≈ 197 MB ----
    ushortT* CCb   = (ushortT*)ws;                        // [8192][2048] bf16
    ushortT* mu_cp = CCb + 1024;                          // strided plane, lda 2048 (CCb right half)
    float*   AbF   = ws + SZ;                             // f32 pre-act (phase 1)
    ushortT* Qa    = (ushortT*)(ws + SZ);                 // overlay after silu
    ushortT* Qb2   = Qa + SZ;
    float*   NbF   = ws + 2 * SZ;
    ushortT* Ka    = (ushortT*)(ws + 2 * SZ);
    ushortT* Kb2   = Ka + SZ;
    ushortT* mu_a  = (ushortT*)(ws + 3 * SZ);             // SZ ushorts
    ushortT* mu_bp = (ushortT*)(ws + 3 * SZ + SZ / 2);    // SZ ushorts
    float*   WVb   = (float*)(ws + 3 * SZ + SZ / 2);      // overlay after projections
    int*     WIb   = (int*)(WVb + MEG);
    ushortT* U     = (ushortT*)(ws + 4 * SZ);             // weights region, 3*MEG floats
    ushortT* Wt_m1 = U;                                   // [1024][2048] = 2M ush
    ushortT* Wt_m2 = U + 2 * MEG;                         // [1024][1024]
    ushortT* Wt_v  = U + 3 * MEG;                         // [1024][1024]
    ushortT* WqT_a = U;            ushortT* WqT_b = U + MEG;     ushortT* WqT_c = U + 2 * MEG;
    ushortT* WkT_a = U + 3 * MEG;  ushortT* WkT_b = U + 4 * MEG; ushortT* WkT_c = U + 5 * MEG;
    ushortT* Wt_o  = U;                                   // [1024][2048], after Q proj
    ushortT* Vb16  = (ushortT*)(ws + 4 * SZ + 3 * MEG);   // SZ ushorts
    ushortT* SbB   = (ushortT*)(ws + 4 * SZ + 3 * MEG + SZ / 2);  // SZ ushorts (then Qc)
    ushortT* Qc    = SbB;
    ushortT* Kc    = (ushortT*)(ws + 4 * SZ + 3 * MEG + SZ);      // SZ ushorts

    dim3 blk256(256);
    dim3 gD(8, 64);

    // 1. mu -> 3 bf16 planes (c strided into CCb right half)
    hipLaunchKernelGGL(split3_mu, dim3(SZ / 4 / 256), blk256, 0, stream, mu, mu_a, mu_bp, CCb);
    // 2. weight transposes (phase A)
    hipLaunchKernelGGL(transpose_f2b, dim3(64, 32), blk256, 0, stream, Wm1, Wt_m1, 2048, 1024);
    hipLaunchKernelGGL(transpose_f2b, dim3(32, 32), blk256, 0, stream, Wm2, Wt_m2, 1024, 1024);
    hipLaunchKernelGGL(transpose_f2b, dim3(32, 32), blk256, 0, stream, Wv, Wt_v, 1024, 1024);
    // 3-4. local pre-acts
    hipLaunchKernelGGL((mfma_gemm<0>), gD, blk256, 0, stream,
                       mu_a, D_, Wt_m1, 2048, bm1, (void*)AbF, D_, D_);
    hipLaunchKernelGGL((mfma_gemm<0>), gD, blk256, 0, stream,
                       mu_a, D_, Wt_m1 + 1024, 2048, (const float*)nullptr, (void*)NbF, D_, D_);
    // 5. silu-mean -> Sb (bf16)
    hipLaunchKernelGGL(silu_mean, dim3(SZ / 4 / 256), blk256, 0, stream, AbF, NbF, SbB);
    // 6. local msgs -> CCb left half
    hipLaunchKernelGGL((mfma_gemm<1>), gD, blk256, 0, stream,
                       SbB, D_, Wt_m2, D_, bm2, (void*)CCb, 2 * D_, D_);
    // 7. V -> bf16
    hipLaunchKernelGGL((mfma_gemm<1>), gD, blk256, 0, stream,
                       mu_a, D_, Wt_v, D_, bv, (void*)Vb16, D_, D_);
    // 8. Wq/Wk -> transposed split planes (phase B overlay)
    hipLaunchKernelGGL(transpose_split3, dim3(32, 32), blk256, 0, stream,
                       Wq, WqT_a, WqT_b, WqT_c, 1024, 1024);
    hipLaunchKernelGGL(transpose_split3, dim3(32, 32), blk256, 0, stream,
                       Wk, WkT_a, WkT_b, WkT_c, 1024, 1024);
    // 9-10. Q/K projections (split-MFMA, f32-equivalent) -> split planes
    hipLaunchKernelGGL(gemm_split6, gD, blk256, 0, stream,
                       mu_a, mu_bp, mu_cp, D_, 2 * D_,
                       WqT_a, WqT_b, WqT_c, bq, Qa, Qb2, Qc);
    hipLaunchKernelGGL(gemm_split6, gD, blk256, 0, stream,
                       mu_a, mu_bp, mu_cp, D_, 2 * D_,
                       WkT_a, WkT_b, WkT_c, bk, Ka, Kb2, Kc);
    // 11. Wo transpose (overlays dead WqT_a/b)
    hipLaunchKernelGGL(transpose_f2b, dim3(64, 32), blk256, 0, stream, Wo, Wt_o, 2048, 1024);
    // 12. scores + per-chunk top-8
    hipLaunchKernelGGL(attn_scores_mfma2, dim3(136, B_), blk256, 0, stream,
                       Qa, Qb2, Qc, Ka, Kb2, Kc, pher, WVb, WIb);
    // 13. merge + softmax + V gather -> CCb right half
    hipLaunchKernelGGL(attn_merge, dim3(M / 4), blk256, 0, stream, WVb, WIb, Vb16, CCb);
    // 14. out = CCb @ Wo + bo
    hipLaunchKernelGGL((mfma_gemm<0>), gD, blk256, 0, stream,
                       CCb, 2 * D_, Wt_o, 2048, bo, (void*)out, D_, 2 * D_);

    (void)in_sizes; (void)n_in; (void)out_size; (void)ws_size;
}